// Round 17
// baseline (156.248 us; speedup 1.0000x reference)
//
#include <hip/hip_runtime.h>
#include <hip/hip_bf16.h>
#include <stdint.h>

#define Bdim 2
#define Sdim 2048
#define Ddim 1024
#define Hdim 16
// DK = 64, BH = 32, M = B*S = 4096

typedef unsigned short u16;
typedef __bf16 bf16x8 __attribute__((ext_vector_type(8)));
typedef float f32x4 __attribute__((ext_vector_type(4)));

__device__ __forceinline__ u16 f2b(float x) {
  return __builtin_bit_cast(u16, (__bf16)x);
}
__device__ __forceinline__ float b2f(u16 u) {
  return __bfloat162float(__builtin_bit_cast(__hip_bfloat16, u));
}
__device__ __forceinline__ f32x4 mfma_bf16(bf16x8 a, bf16x8 b, f32x4 c) {
  return __builtin_amdgcn_mfma_f32_16x16x32_bf16(a, b, c, 0, 0, 0);
}
__device__ __forceinline__ void gload_lds16(const u16* gp, u16* lp) {
  __builtin_amdgcn_global_load_lds(
      (const __attribute__((address_space(1))) void*)gp,
      (__attribute__((address_space(3))) void*)lp, 16, 0, 0);
}

#if __has_builtin(__builtin_amdgcn_exp2f)
#define EXP2(x) __builtin_amdgcn_exp2f(x)
#else
#define EXP2(x) exp2f(x)
#endif

// piece schedule: 72 pieces/head, ALL <=4 chunks (64-key units). 2304 blocks
// = 9/CU queued; max serial chain 4 chunks. u>=2 writes partial slot u-2.
__constant__ uint8_t PT_tile[72] = {
  0,1, 2,2, 3,3, 4,4,4, 5,5,5, 6,6,6,6, 7,7,7,7,
  8,8,8,8,8, 9,9,9,9,9, 10,10,10,10,10,10, 11,11,11,11,11,11,
  12,12,12,12,12,12,12, 13,13,13,13,13,13,13,
  14,14,14,14,14,14,14,14, 15,15,15,15,15,15,15,15};
__constant__ uint8_t PT_c0[72] = {
  0, 0, 0,3, 0,4, 0,4,7, 0,4,8, 0,4,8,11, 0,4,8,12,
  0,4,8,12,15, 0,4,8,12,16, 0,4,8,12,16,19, 0,4,8,12,16,20,
  0,4,8,12,16,20,23, 0,4,8,12,16,20,24,
  0,4,8,12,16,20,24,27, 0,4,8,12,16,20,24,28};
__constant__ uint8_t PT_c1[72] = {
  2, 4, 3,6, 4,8, 4,7,10, 4,8,12, 4,8,11,14, 4,8,12,16,
  4,8,12,15,18, 4,8,12,16,20, 4,8,12,16,19,22, 4,8,12,16,20,24,
  4,8,12,16,20,23,26, 4,8,12,16,20,24,28,
  4,8,12,16,20,24,27,30, 4,8,12,16,20,24,28,32};
// combine: tiles 2..15
__constant__ uint8_t CB_base[14] = {0,2,4,7,10,14,18,23,28,34,40,47,54,62};
__constant__ uint8_t CB_cnt[14]  = {2,2,3,3,4,4,5,5,6,6,7,7,8,8};

// ---------------------------------------------------------------------------
// Kernel 1: fp32 -> bf16 conversion of q,k,v and the 4 weights.
// ---------------------------------------------------------------------------
__global__ __launch_bounds__(256) void k_convert(
    const float* __restrict__ q, const float* __restrict__ k, const float* __restrict__ v,
    const float* __restrict__ wq, const float* __restrict__ wk,
    const float* __restrict__ wv, const float* __restrict__ wo,
    u16* __restrict__ qb, u16* __restrict__ kb, u16* __restrict__ vb,
    u16* __restrict__ wqb, u16* __restrict__ wkb, u16* __restrict__ wvb, u16* __restrict__ wob) {
  int i = (blockIdx.x * 256 + threadIdx.x) * 4;
  const float* src;
  u16* dst;
  int off;
  if (i < 12582912) {              // 3 * 4Mi
    int s = i >> 22;
    off = i - (s << 22);
    src = (s == 0) ? q : ((s == 1) ? k : v);
    dst = (s == 0) ? qb : ((s == 1) ? kb : vb);
  } else {
    int j = i - 12582912;
    int s = j >> 20;
    off = j - (s << 20);
    src = (s == 0) ? wq : ((s == 1) ? wk : ((s == 2) ? wv : wo));
    dst = (s == 0) ? wqb : ((s == 1) ? wkb : ((s == 2) ? wvb : wob));
  }
  float4 f = *(const float4*)(src + off);
  ushort4 o;
  o.x = f2b(f.x); o.y = f2b(f.y); o.z = f2b(f.z); o.w = f2b(f.w);
  *(ushort4*)(dst + off) = o;
}

// ---------------------------------------------------------------------------
// Kernel 2: RoPE cos/sin table, [S][32] each, fp32.
// ---------------------------------------------------------------------------
__global__ __launch_bounds__(256) void k_ropetab(float* __restrict__ cosT, float* __restrict__ sinT) {
  int i = blockIdx.x * 256 + threadIdx.x;   // 0 .. 65536
  int s = i >> 5, j = i & 31;
  float invf = expf(-(float)j * 0.28782313662425574f);  // ln(1e4)/32
  float ang = (float)s * invf;
  float sn, cs;
  sincosf(ang, &sn, &cs);
  cosT[i] = cs;
  sinT[i] = sn;
}

// ---------------------------------------------------------------------------
// Kernel 3: fused QKV projection GEMM -- exact R14 config (measured optimum:
// 44.6us). BM=64 x BN=128, BK=64, 4 waves of 32x64, 24KB LDS, 6 blocks/CU.
// T21 granule swizzle: pre-swizzled source + XOR read (2-way, free).
// z=0: Q (RoPE+0.125*log2e -> Qr), z=1: K (RoPE -> Kr), z=2: V (per-wave
// 32x64 LDS transpose -> Vt kappa-order, private LDS regions).
// ---------------------------------------------------------------------------
__global__ __launch_bounds__(256) void k_gemmQKV(
    const u16* __restrict__ A0, const u16* __restrict__ W0,
    const u16* __restrict__ A1, const u16* __restrict__ W1,
    const u16* __restrict__ A2, const u16* __restrict__ W2,
    const float* __restrict__ cosT, const float* __restrict__ sinT,
    u16* __restrict__ Qr, u16* __restrict__ Kr, u16* __restrict__ Vt) {
  const int z = blockIdx.z;
  const u16* A = (z == 0) ? A0 : ((z == 1) ? A1 : A2);
  const u16* W = (z == 0) ? W0 : ((z == 1) ? W1 : W2);

  __shared__ u16 SL[12288];   // As = SL[0..4095] (64x64), Bs = SL[4096..12287] (128x64)
  u16* As = &SL[0];
  u16* Bs = &SL[4096];

  const int tid = threadIdx.x;
  const int wave = tid >> 6, lane = tid & 63;
  const int g = lane >> 4, cc = lane & 15;
  const int wm = wave >> 1, wn = wave & 1;
  const int row0 = blockIdx.x * 64, col0 = blockIdx.y * 128;

  const int rl8 = lane >> 3;
  const int sg8 = (lane & 7) ^ rl8;
  const u16* Asrc = A + (size_t)(row0 + wave * 16 + rl8) * 1024 + sg8 * 8;
  const u16* Wsrc = W + (size_t)(col0 + wave * 32 + rl8) * 1024 + sg8 * 8;
  u16* adst = &As[wave * 1024];
  u16* bdst = &Bs[wave * 2048];

  f32x4 acc[2][4] = {};

  for (int t = 0; t < 16; ++t) {
    const int k0 = t * 64;
    __syncthreads();
#pragma unroll
    for (int i = 0; i < 2; ++i)
      gload_lds16(Asrc + (size_t)i * 8192 + k0, adst + i * 512);
#pragma unroll
    for (int j = 0; j < 4; ++j)
      gload_lds16(Wsrc + (size_t)j * 8192 + k0, bdst + j * 512);
    __syncthreads();
#pragma unroll
    for (int hk = 0; hk < 2; ++hk) {
      bf16x8 af[2], bfv[4];
#pragma unroll
      for (int mi = 0; mi < 2; ++mi) {
        const int R = wm * 32 + mi * 16 + cc;
        af[mi] = *(const bf16x8*)&As[R * 64 + (((hk * 4 + g) ^ (R & 7)) * 8)];
      }
#pragma unroll
      for (int ni = 0; ni < 4; ++ni) {
        const int R = wn * 64 + ni * 16 + cc;
        bfv[ni] = *(const bf16x8*)&Bs[R * 64 + (((hk * 4 + g) ^ (R & 7)) * 8)];
      }
#pragma unroll
      for (int mi = 0; mi < 2; ++mi)
#pragma unroll
        for (int ni = 0; ni < 4; ++ni)
          acc[mi][ni] = mfma_bf16(af[mi], bfv[ni], acc[mi][ni]);
    }
  }

  const int hgl = (col0 >> 6) + wn;    // global head 0..15 (64 cols per wave)

  if (z < 2) {
    const float scale = (z == 0) ? 0.18033688011112042f : 1.0f;  // 0.125*log2e
    u16* dbase = (z == 0) ? Qr : Kr;
#pragma unroll
    for (int mi = 0; mi < 2; ++mi)
#pragma unroll
      for (int r = 0; r < 4; ++r) {
        const int gr = row0 + wm * 32 + mi * 16 + g * 4 + r;
        const int bb = gr >> 11, s = gr & 2047;
        const float cv0 = cosT[s * 32 + cc],      sv0 = sinT[s * 32 + cc];
        const float cv1 = cosT[s * 32 + cc + 16], sv1 = sinT[s * 32 + cc + 16];
        const float x0 = acc[mi][0][r], x1 = acc[mi][1][r];
        const float x2 = acc[mi][2][r], x3 = acc[mi][3][r];
        u16* dst = dbase + ((size_t)((bb * 16 + hgl) * 2048 + s)) * 64;
        dst[cc]      = f2b((x0 * cv0 - x2 * sv0) * scale);
        dst[cc + 16] = f2b((x1 * cv1 - x3 * sv1) * scale);
        dst[cc + 32] = f2b((x2 * cv0 + x0 * sv0) * scale);
        dst[cc + 48] = f2b((x3 * cv1 + x1 * sv1) * scale);
      }
  } else {
    // V: per-wave 32(s) x 64(dk) transpose via private LDS tl[32][72]
    u16* tl = &SL[wave * 2304];       // 32*72 = 2304 u16 per wave
    __syncthreads();
#pragma unroll
    for (int mi = 0; mi < 2; ++mi)
#pragma unroll
      for (int ni = 0; ni < 4; ++ni)
#pragma unroll
        for (int r = 0; r < 4; ++r)
          tl[(mi * 16 + g * 4 + r) * 72 + ni * 16 + cc] = f2b(acc[mi][ni][r]);
    asm volatile("s_waitcnt lgkmcnt(0)" ::: "memory");
    __builtin_amdgcn_sched_barrier(0);
#pragma unroll
    for (int p2 = 0; p2 < 8; ++p2) {
      const int dr = p2 * 8 + (lane >> 3);        // dk row 0..63
      const int scr = (lane & 7) * 4;             // s (rel to wave), %4 == 0
      ushort4 o;
      o.x = tl[(scr + 0) * 72 + dr];
      o.y = tl[(scr + 1) * 72 + dr];
      o.z = tl[(scr + 2) * 72 + dr];
      o.w = tl[(scr + 3) * 72 + dr];
      const int gsr = row0 + wm * 32 + scr;
      const int bb = gsr >> 11, sb = gsr & 2047;
      const int cch = sb >> 5, kap = sb & 31;
      const int pos = (cch << 5) + (((kap >> 2) & 3) << 3) + ((kap >> 4) << 2);
      *(ushort4*)(Vt + ((size_t)((bb * 16 + hgl) * 64 + dr)) * 2048 + pos) = o;
    }
  }
}

// ---------------------------------------------------------------------------
// Kernel 3b: output projection GEMM, fp32 out, exact R14 structure.
// ---------------------------------------------------------------------------
__global__ __launch_bounds__(256) void k_gemmO(
    const u16* __restrict__ A, const u16* __restrict__ W, float* __restrict__ O) {
  __shared__ u16 SL[12288];
  u16* As = &SL[0];
  u16* Bs = &SL[4096];

  const int tid = threadIdx.x;
  const int wave = tid >> 6, lane = tid & 63;
  const int g = lane >> 4, cc = lane & 15;
  const int wm = wave >> 1, wn = wave & 1;
  const int row0 = blockIdx.x * 64, col0 = blockIdx.y * 128;

  const int rl8 = lane >> 3;
  const int sg8 = (lane & 7) ^ rl8;
  const u16* Asrc = A + (size_t)(row0 + wave * 16 + rl8) * 1024 + sg8 * 8;
  const u16* Wsrc = W + (size_t)(col0 + wave * 32 + rl8) * 1024 + sg8 * 8;
  u16* adst = &As[wave * 1024];
  u16* bdst = &Bs[wave * 2048];

  f32x4 acc[2][4] = {};

  for (int t = 0; t < 16; ++t) {
    const int k0 = t * 64;
    __syncthreads();
#pragma unroll
    for (int i = 0; i < 2; ++i)
      gload_lds16(Asrc + (size_t)i * 8192 + k0, adst + i * 512);
#pragma unroll
    for (int j = 0; j < 4; ++j)
      gload_lds16(Wsrc + (size_t)j * 8192 + k0, bdst + j * 512);
    __syncthreads();
#pragma unroll
    for (int hk = 0; hk < 2; ++hk) {
      bf16x8 af[2], bfv[4];
#pragma unroll
      for (int mi = 0; mi < 2; ++mi) {
        const int R = wm * 32 + mi * 16 + cc;
        af[mi] = *(const bf16x8*)&As[R * 64 + (((hk * 4 + g) ^ (R & 7)) * 8)];
      }
#pragma unroll
      for (int ni = 0; ni < 4; ++ni) {
        const int R = wn * 64 + ni * 16 + cc;
        bfv[ni] = *(const bf16x8*)&Bs[R * 64 + (((hk * 4 + g) ^ (R & 7)) * 8)];
      }
#pragma unroll
      for (int mi = 0; mi < 2; ++mi)
#pragma unroll
        for (int ni = 0; ni < 4; ++ni)
          acc[mi][ni] = mfma_bf16(af[mi], bfv[ni], acc[mi][ni]);
    }
  }

#pragma unroll
  for (int mi = 0; mi < 2; ++mi)
#pragma unroll
    for (int ni = 0; ni < 4; ++ni)
#pragma unroll
      for (int r = 0; r < 4; ++r) {
        const int row = row0 + wm * 32 + mi * 16 + g * 4 + r;
        const int col = col0 + wn * 64 + ni * 16 + cc;
        O[row * 1024 + col] = acc[mi][ni][r];
      }
}

// ---------------------------------------------------------------------------
// Kernel 6: causal flash attention, fine split-K (2304 blocks, <=4 chunks
// per piece). No VGPR clamp. Native v_exp_f32. Stage issued before Q loads.
// ---------------------------------------------------------------------------
template <int M0, int M1>   // per 32-key half: 0=full, 1=tri(diag), 2=skip
__device__ __forceinline__ void attn_chunk64(
    const u16* __restrict__ kl, const u16* __restrict__ vl, int cc, int g,
    const bf16x8 qf[4],
    float& mold0, float& mold1, float& lsum0, float& lsum1,
    f32x4 ot0[4], f32x4 ot1[4]) {
  const int m7 = cc & 7;
  const int gA = (g ^ m7) * 8;
  const int gB = ((g + 4) ^ m7) * 8;

  f32x4 x0A0 = {}, x0B0 = {}, x0A1 = {}, x0B1 = {};
  {
    const u16* r0 = kl + cc * 64;
    const u16* r1 = kl + (16 + cc) * 64;
    bf16x8 k0 = *(const bf16x8*)(r0 + gA);
    bf16x8 k1 = *(const bf16x8*)(r0 + gB);
    bf16x8 k2 = *(const bf16x8*)(r1 + gA);
    bf16x8 k3 = *(const bf16x8*)(r1 + gB);
    x0A0 = mfma_bf16(k0, qf[0], x0A0);
    x0A0 = mfma_bf16(k1, qf[1], x0A0);
    x0B0 = mfma_bf16(k2, qf[0], x0B0);
    x0B0 = mfma_bf16(k3, qf[1], x0B0);
    x0A1 = mfma_bf16(k0, qf[2], x0A1);
    x0A1 = mfma_bf16(k1, qf[3], x0A1);
    x0B1 = mfma_bf16(k2, qf[2], x0B1);
    x0B1 = mfma_bf16(k3, qf[3], x0B1);
  }
  f32x4 x1A0 = {}, x1B0 = {}, x1A1 = {}, x1B1 = {};
  if (M1 != 2) {
    const u16* r0 = kl + (32 + cc) * 64;
    const u16* r1 = kl + (48 + cc) * 64;
    bf16x8 k0 = *(const bf16x8*)(r0 + gA);
    bf16x8 k1 = *(const bf16x8*)(r0 + gB);
    bf16x8 k2 = *(const bf16x8*)(r1 + gA);
    bf16x8 k3 = *(const bf16x8*)(r1 + gB);
    x1A0 = mfma_bf16(k0, qf[0], x1A0);
    x1A0 = mfma_bf16(k1, qf[1], x1A0);
    x1B0 = mfma_bf16(k2, qf[0], x1B0);
    x1B0 = mfma_bf16(k3, qf[1], x1B0);
    x1A1 = mfma_bf16(k0, qf[2], x1A1);
    x1A1 = mfma_bf16(k1, qf[3], x1A1);
    x1B1 = mfma_bf16(k2, qf[2], x1B1);
    x1B1 = mfma_bf16(k3, qf[3], x1B1);
  }

  float p0[16], p1[16];
#pragma unroll
  for (int r = 0; r < 4; ++r) {
    const int ka = g * 4 + r;
    float a0 = x0A0[r], b0 = x0B0[r], a1 = x0A1[r], b1 = x0B1[r];
    if (M0 == 1) {
      a0 = (ka <= cc) ? a0 : -30000.0f;
      b0 = -30000.0f;
      b1 = (ka <= cc) ? b1 : -30000.0f;
    }
    p0[r] = a0; p0[4 + r] = b0;
    p1[r] = a1; p1[4 + r] = b1;
  }
  if (M1 != 2) {
#pragma unroll
    for (int r = 0; r < 4; ++r) {
      const int ka = g * 4 + r;
      float a0 = x1A0[r], b0 = x1B0[r], a1 = x1A1[r], b1 = x1B1[r];
      if (M1 == 1) {
        a0 = (ka <= cc) ? a0 : -30000.0f;
        b0 = -30000.0f;
        b1 = (ka <= cc) ? b1 : -30000.0f;
      }
      p0[8 + r] = a0; p0[12 + r] = b0;
      p1[8 + r] = a1; p1[12 + r] = b1;
    }
  }

  float m0, m1;
  if (M1 != 2) {
    float t0a = fmaxf(fmaxf(p0[0], p0[1]), p0[2]);
    float t0b = fmaxf(fmaxf(p0[3], p0[4]), p0[5]);
    float t0c = fmaxf(fmaxf(p0[6], p0[7]), p0[8]);
    float t0d = fmaxf(fmaxf(p0[9], p0[10]), p0[11]);
    float t0e = fmaxf(fmaxf(p0[12], p0[13]), p0[14]);
    m0 = fmaxf(fmaxf(fmaxf(t0a, t0b), fmaxf(t0c, t0d)), fmaxf(t0e, p0[15]));
    float t1a = fmaxf(fmaxf(p1[0], p1[1]), p1[2]);
    float t1b = fmaxf(fmaxf(p1[3], p1[4]), p1[5]);
    float t1c = fmaxf(fmaxf(p1[6], p1[7]), p1[8]);
    float t1d = fmaxf(fmaxf(p1[9], p1[10]), p1[11]);
    float t1e = fmaxf(fmaxf(p1[12], p1[13]), p1[14]);
    m1 = fmaxf(fmaxf(fmaxf(t1a, t1b), fmaxf(t1c, t1d)), fmaxf(t1e, p1[15]));
  } else {
    float t0a = fmaxf(fmaxf(p0[0], p0[1]), p0[2]);
    float t0b = fmaxf(fmaxf(p0[3], p0[4]), p0[5]);
    m0 = fmaxf(fmaxf(p0[6], p0[7]), fmaxf(t0a, t0b));
    float t1a = fmaxf(fmaxf(p1[0], p1[1]), p1[2]);
    float t1b = fmaxf(fmaxf(p1[3], p1[4]), p1[5]);
    m1 = fmaxf(fmaxf(p1[6], p1[7]), fmaxf(t1a, t1b));
  }

  // shuffle-free defer test (mold is row-uniform by construction)
  if (!__all((m0 <= mold0 + 11.5f) && (m1 <= mold1 + 11.5f))) {
    float M0v = fmaxf(m0, __shfl_xor(m0, 16));
    M0v = fmaxf(M0v, __shfl_xor(M0v, 32));
    float M1v = fmaxf(m1, __shfl_xor(m1, 16));
    M1v = fmaxf(M1v, __shfl_xor(M1v, 32));
    M0v = fmaxf(mold0, M0v);
    M1v = fmaxf(mold1, M1v);
    const float al0 = EXP2(mold0 - M0v), al1 = EXP2(mold1 - M1v);
    mold0 = M0v; mold1 = M1v;
    lsum0 *= al0; lsum1 *= al1;
#pragma unroll
    for (int dc = 0; dc < 4; ++dc) { ot0[dc] *= al0; ot1[dc] *= al1; }
  }

  float rs0 = 0.f, rs1 = 0.f;
  bf16x8 a0v, a1v, b0v2, b1v2;
#pragma unroll
  for (int j = 0; j < 8; ++j) {
    float e0 = EXP2(p0[j] - mold0);
    float e1 = EXP2(p1[j] - mold1);
    rs0 += e0; rs1 += e1;
    a0v[j] = (__bf16)e0;
    a1v[j] = (__bf16)e1;
  }
  if (M1 != 2) {
#pragma unroll
    for (int j = 0; j < 8; ++j) {
      float e0 = EXP2(p0[8 + j] - mold0);
      float e1 = EXP2(p1[8 + j] - mold1);
      rs0 += e0; rs1 += e1;
      b0v2[j] = (__bf16)e0;
      b1v2[j] = (__bf16)e1;
    }
  }
  lsum0 += rs0; lsum1 += rs1;

#pragma unroll
  for (int dc = 0; dc < 4; ++dc) {
    bf16x8 vv = *(const bf16x8*)(vl + (dc * 16 + cc) * 64 + gA);
    ot0[dc] = mfma_bf16(vv, a0v, ot0[dc]);
    ot1[dc] = mfma_bf16(vv, a1v, ot1[dc]);
  }
  if (M1 != 2) {
#pragma unroll
    for (int dc = 0; dc < 4; ++dc) {
      bf16x8 vv = *(const bf16x8*)(vl + (dc * 16 + cc) * 64 + gB);
      ot0[dc] = mfma_bf16(vv, b0v2, ot0[dc]);
      ot1[dc] = mfma_bf16(vv, b1v2, ot1[dc]);
    }
  }
}

__global__ __launch_bounds__(256) void k_attn(
    const u16* __restrict__ Qr, const u16* __restrict__ Kr,
    const u16* __restrict__ Vt, u16* __restrict__ Oc,
    u16* __restrict__ PO, float* __restrict__ PML) {
  __shared__ u16 Kl[2][4096];   // [buf][64 keys x 64 d], granule-swizzled
  __shared__ u16 Vl[2][4096];   // [buf][64 d x 64 keys], granule-swizzled

  const int x = blockIdx.x;          // 0..2303
  const int bh = x & 31;             // all pieces of head bh -> XCD bh%8
  const int u = 71 - (x >> 5);       // heavy pieces first
  const int tile = PT_tile[u];
  const int c0 = PT_c0[u];
  const int c1 = PT_c1[u];
  const int slot = u - 2;            // <0 => direct output (tiles 0,1)
  const int b = bh >> 4, h = bh & 15;
  const int tid = threadIdx.x;
  const int w = tid >> 6;
  const int lane = tid & 63;
  const int g = lane >> 4, cc = lane & 15;

  const int qrow0 = tile * 128 + w * 32;
  const int myDiag = 2 * tile + (w >> 1);

  const u16* Kp = Kr + (size_t)bh * (Sdim * 64);
  const u16* Vp = Vt + (size_t)bh * (64 * Sdim);
  const u16* Qp = Qr + (size_t)(bh * Sdim + qrow0) * 64;

  // staging sources (pre-swizzled, T21): granule ^= row_local&7
  const int rloc = lane >> 3;
  const int sg = (lane & 7) ^ rloc;
  const u16* kS = Kp + (size_t)(w * 16 + rloc) * 64 + sg * 8;
  const u16* vS = Vp + (size_t)(w * 16 + rloc) * 2048 + sg * 8;

  auto stageKV = [&](int t, int buf) {
    const size_t ko = (size_t)t * 4096;
    const size_t vo = (size_t)t * 64;
    gload_lds16(kS + ko, &Kl[buf][w * 1024]);
    gload_lds16(kS + ko + 512, &Kl[buf][w * 1024 + 512]);
    gload_lds16(vS + vo, &Vl[buf][w * 1024]);
    gload_lds16(vS + vo + 16384, &Vl[buf][w * 1024 + 512]);
  };

  stageKV(c0, c0 & 1);               // earliest DMA start

  bf16x8 qf[4];
  qf[0] = *(const bf16x8*)(Qp + cc * 64 + g * 8);
  qf[1] = *(const bf16x8*)(Qp + cc * 64 + g * 8 + 32);
  qf[2] = *(const bf16x8*)(Qp + (16 + cc) * 64 + g * 8);
  qf[3] = *(const bf16x8*)(Qp + (16 + cc) * 64 + g * 8 + 32);

  float mold0 = -1e30f, mold1 = -1e30f, lsum0 = 0.f, lsum1 = 0.f;
  f32x4 ot0[4] = {}, ot1[4] = {};

  for (int t = c0; t < c1; ++t) {
    __syncthreads();                 // drains stage(t)
    if (t + 1 < c1) stageKV(t + 1, (t + 1) & 1);
    if (t <= myDiag) {
      const u16* kl = &Kl[t & 1][0];
      const u16* vl = &Vl[t & 1][0];
      if (t < myDiag)
        attn_chunk64<0, 0>(kl, vl, cc, g, qf, mold0, mold1, lsum0, lsum1, ot0, ot1);
      else if (w & 1)
        attn_chunk64<0, 1>(kl, vl, cc, g, qf, mold0, mold1, lsum0, lsum1, ot0, ot1);
      else
        attn_chunk64<1, 2>(kl, vl, cc, g, qf, mold0, mold1, lsum0, lsum1, ot0, ot1);
    }
  }

  float l0 = lsum0 + __shfl_xor(lsum0, 16);
  l0 += __shfl_xor(l0, 32);
  float l1 = lsum1 + __shfl_xor(lsum1, 16);
  l1 += __shfl_xor(l1, 32);

  if (slot < 0) {
    const float rl0 = 1.0f / l0, rl1 = 1.0f / l1;
    u16* dst0 = Oc + (size_t)(b * Sdim + qrow0 + cc) * Ddim + h * 64 + g * 4;
    u16* dst1 = dst0 + 16 * Ddim;
#pragma unroll
    for (int dc = 0; dc < 4; ++dc) {
      ushort4 o0, o1;
      o0.x = f2b(ot0[dc][0] * rl0);
      o0.y = f2b(ot0[dc][1] * rl0);
      o0.z = f2b(ot0[dc][2] * rl0);
      o0.w = f2b(ot0[dc][3] * rl0);
      o1.x = f2b(ot1[dc][0] * rl1);
      o1.y = f2b(ot1[dc][1] * rl1);
      o1.z = f2b(ot1[dc][2] * rl1);
      o1.w = f2b(ot1[dc][3] * rl1);
      *(ushort4*)(dst0 + dc * 16) = o0;
      *(ushort4*)(dst1 + dc * 16) = o1;
    }
  } else {
    const int sgl = bh * 70 + slot;
    u16* po0 = PO + (size_t)sgl * 8192 + (w * 32 + cc) * 64;
    u16* po1 = po0 + 16 * 64;
#pragma unroll
    for (int dc = 0; dc < 4; ++dc) {
      ushort4 o0, o1;
      o0.x = f2b(ot0[dc][0]); o0.y = f2b(ot0[dc][1]);
      o0.z = f2b(ot0[dc][2]); o0.w = f2b(ot0[dc][3]);
      o1.x = f2b(ot1[dc][0]); o1.y = f2b(ot1[dc][1]);
      o1.z = f2b(ot1[dc][2]); o1.w = f2b(ot1[dc][3]);
      *(ushort4*)(po0 + dc * 16 + g * 4) = o0;
      *(ushort4*)(po1 + dc * 16 + g * 4) = o1;
    }
    if (g == 0) {
      float* ml = PML + (size_t)sgl * 256 + (w * 32 + cc) * 2;
      ml[0] = mold0;
      ml[1] = l0;
      ml[32] = mold1;
      ml[33] = l1;
    }
  }
}

// ---------------------------------------------------------------------------
// Kernel 7: combine split-K partials for tiles 2..15 (2-8 pieces each).
// ---------------------------------------------------------------------------
__global__ __launch_bounds__(128) void k_comb(
    const u16* __restrict__ PO, const float* __restrict__ PML,
    u16* __restrict__ Oc) {
  const int x = blockIdx.x;          // 0..447: bh fastest (XCD-local)
  const int bh = x & 31;
  const int tidx = x >> 5;           // 0..13
  const int tile = tidx + 2;
  const int cnt = CB_cnt[tidx];
  const int sgb = bh * 70 + CB_base[tidx];
  const int b = bh >> 4, h = bh & 15;
  const int r = threadIdx.x;         // row 0..127

  float m[8], l[8];
#pragma unroll
  for (int j = 0; j < 8; ++j) {
    if (j < cnt) {
      const float* ml = PML + (size_t)(sgb + j) * 256 + r * 2;
      m[j] = ml[0];
      l[j] = ml[1];
    } else { m[j] = -1e30f; l[j] = 0.f; }
  }
  float M = m[0];
#pragma unroll
  for (int j = 1; j < 8; ++j) M = fmaxf(M, m[j]);
  float wgt[8];
  float ltot = 0.f;
#pragma unroll
  for (int j = 0; j < 8; ++j) {
    wgt[j] = (j < cnt) ? EXP2(m[j] - M) : 0.f;
    ltot += wgt[j] * l[j];
  }
  const float inv = 1.0f / ltot;
#pragma unroll
  for (int j = 0; j < 8; ++j) wgt[j] *= inv;

  u16* dst = Oc + (size_t)(b * Sdim + tile * 128 + r) * Ddim + h * 64;
#pragma unroll
  for (int c = 0; c < 64; c += 4) {
    float acc0 = 0.f, acc1 = 0.f, acc2 = 0.f, acc3 = 0.f;
#pragma unroll
    for (int j = 0; j < 8; ++j) {
      if (j < cnt) {
        ushort4 pv = *(const ushort4*)(PO + (size_t)(sgb + j) * 8192 + r * 64 + c);
        acc0 += wgt[j] * b2f(pv.x);
        acc1 += wgt[j] * b2f(pv.y);
        acc2 += wgt[j] * b2f(pv.z);
        acc3 += wgt[j] * b2f(pv.w);
      }
    }
    ushort4 o;
    o.x = f2b(acc0); o.y = f2b(acc1); o.z = f2b(acc2); o.w = f2b(acc3);
    *(ushort4*)(dst + c) = o;
  }
}

// ---------------------------------------------------------------------------
extern "C" void kernel_launch(void* const* d_in, const int* in_sizes, int n_in,
                              void* d_out, int out_size, void* d_ws, size_t ws_size,
                              hipStream_t stream) {
  const float* q = (const float*)d_in[0];
  const float* k = (const float*)d_in[1];
  const float* v = (const float*)d_in[2];
  const float* wq = (const float*)d_in[3];
  const float* wk = (const float*)d_in[4];
  const float* wv = (const float*)d_in[5];
  const float* wo = (const float*)d_in[6];
  float* out = (float*)d_out;

  uint8_t* ws = (uint8_t*)d_ws;
  const size_t MiB = 1ull << 20;
  // Liveness map:
  //  phase 1 (convert/gemmQKV): qb 0-8, kb 8-16, vb 16-24, wqb/wkb/wvb 24-30,
  //                             wob 48-50 (LIVE until k_gemmO!), tables 88+.
  //  phase 2 (attn/comb):       PO 0-36.7, PML 40-42.3 (over dead qb/kb/vb/wq..),
  //                             Qr 56, Kr 64, Vt 72, Oc 80-88.
  //  phase 3 (gemmO):           Oc + wob(48-50) -> out.
  u16* qb  = (u16*)(ws + 0 * MiB);
  u16* kb  = (u16*)(ws + 8 * MiB);
  u16* vb  = (u16*)(ws + 16 * MiB);
  u16* wqb = (u16*)(ws + 24 * MiB);
  u16* wkb = (u16*)(ws + 26 * MiB);
  u16* wvb = (u16*)(ws + 28 * MiB);
  u16* wob = (u16*)(ws + 48 * MiB);      // moved out of PO's range (R16 bug)
  u16* Qr  = (u16*)(ws + 56 * MiB);
  u16* Kr  = (u16*)(ws + 64 * MiB);
  u16* Vt  = (u16*)(ws + 72 * MiB);
  u16* Oc  = (u16*)(ws + 80 * MiB);
  float* cosT = (float*)(ws + 88 * MiB);
  float* sinT = (float*)(ws + 88 * MiB + 256 * 1024);
  u16*   PO  = (u16*)(ws + 0 * MiB);     // 2240 slots * 8192 bf16 = 36.7 MB
  float* PML = (float*)(ws + 40 * MiB);  // 2240 * 256 f32 = 2.29 MB

  k_convert<<<16384, 256, 0, stream>>>(q, k, v, wq, wk, wv, wo,
                                       qb, kb, vb, wqb, wkb, wvb, wob);
  k_ropetab<<<256, 256, 0, stream>>>(cosT, sinT);
  k_gemmQKV<<<dim3(64, 8, 3), 256, 0, stream>>>(qb, wqb, kb, wkb, vb, wvb,
                                                cosT, sinT, Qr, Kr, Vt);
  k_attn<<<2304, 256, 0, stream>>>(Qr, Kr, Vt, Oc, PO, PML);
  k_comb<<<448, 128, 0, stream>>>(PO, PML, Oc);
  k_gemmO<<<dim3(64, 8), 256, 0, stream>>>(Oc, wob, out);
}

// Round 18
// 115.646 us; speedup vs baseline: 1.3511x; 1.3511x over previous
//
#include <hip/hip_runtime.h>
#include <hip/hip_bf16.h>
#include <stdint.h>

#define Bdim 2
#define Sdim 2048
#define Ddim 1024
#define Hdim 16
// DK = 64, BH = 32, M = B*S = 4096

typedef unsigned short u16;
typedef __bf16 bf16x8 __attribute__((ext_vector_type(8)));
typedef float f32x4 __attribute__((ext_vector_type(4)));

__device__ __forceinline__ u16 f2b(float x) {
  return __builtin_bit_cast(u16, (__bf16)x);
}
__device__ __forceinline__ float b2f(u16 u) {
  return __bfloat162float(__builtin_bit_cast(__hip_bfloat16, u));
}
__device__ __forceinline__ f32x4 mfma_bf16(bf16x8 a, bf16x8 b, f32x4 c) {
  return __builtin_amdgcn_mfma_f32_16x16x32_bf16(a, b, c, 0, 0, 0);
}
__device__ __forceinline__ void gload_lds16(const u16* gp, u16* lp) {
  __builtin_amdgcn_global_load_lds(
      (const __attribute__((address_space(1))) void*)gp,
      (__attribute__((address_space(3))) void*)lp, 16, 0, 0);
}

#if __has_builtin(__builtin_amdgcn_exp2f)
#define EXP2(x) __builtin_amdgcn_exp2f(x)
#else
#define EXP2(x) exp2f(x)
#endif

// piece schedule: 72 pieces/head, ALL <=4 chunks (64-key units). 2304 blocks
// = 9/CU queued; max serial chain 4 chunks. u>=2 writes partial slot u-2.
__constant__ uint8_t PT_tile[72] = {
  0,1, 2,2, 3,3, 4,4,4, 5,5,5, 6,6,6,6, 7,7,7,7,
  8,8,8,8,8, 9,9,9,9,9, 10,10,10,10,10,10, 11,11,11,11,11,11,
  12,12,12,12,12,12,12, 13,13,13,13,13,13,13,
  14,14,14,14,14,14,14,14, 15,15,15,15,15,15,15,15};
__constant__ uint8_t PT_c0[72] = {
  0, 0, 0,3, 0,4, 0,4,7, 0,4,8, 0,4,8,11, 0,4,8,12,
  0,4,8,12,15, 0,4,8,12,16, 0,4,8,12,16,19, 0,4,8,12,16,20,
  0,4,8,12,16,20,23, 0,4,8,12,16,20,24,
  0,4,8,12,16,20,24,27, 0,4,8,12,16,20,24,28};
__constant__ uint8_t PT_c1[72] = {
  2, 4, 3,6, 4,8, 4,7,10, 4,8,12, 4,8,11,14, 4,8,12,16,
  4,8,12,15,18, 4,8,12,16,20, 4,8,12,16,19,22, 4,8,12,16,20,24,
  4,8,12,16,20,23,26, 4,8,12,16,20,24,28,
  4,8,12,16,20,24,27,30, 4,8,12,16,20,24,28,32};
// combine: tiles 2..15
__constant__ uint8_t CB_base[14] = {0,2,4,7,10,14,18,23,28,34,40,47,54,62};
__constant__ uint8_t CB_cnt[14]  = {2,2,3,3,4,4,5,5,6,6,7,7,8,8};

// ---------------------------------------------------------------------------
// Kernel 1: fp32 -> bf16 conversion of q,k,v and the 4 weights.
// ---------------------------------------------------------------------------
__global__ __launch_bounds__(256) void k_convert(
    const float* __restrict__ q, const float* __restrict__ k, const float* __restrict__ v,
    const float* __restrict__ wq, const float* __restrict__ wk,
    const float* __restrict__ wv, const float* __restrict__ wo,
    u16* __restrict__ qb, u16* __restrict__ kb, u16* __restrict__ vb,
    u16* __restrict__ wqb, u16* __restrict__ wkb, u16* __restrict__ wvb, u16* __restrict__ wob) {
  int i = (blockIdx.x * 256 + threadIdx.x) * 4;
  const float* src;
  u16* dst;
  int off;
  if (i < 12582912) {              // 3 * 4Mi
    int s = i >> 22;
    off = i - (s << 22);
    src = (s == 0) ? q : ((s == 1) ? k : v);
    dst = (s == 0) ? qb : ((s == 1) ? kb : vb);
  } else {
    int j = i - 12582912;
    int s = j >> 20;
    off = j - (s << 20);
    src = (s == 0) ? wq : ((s == 1) ? wk : ((s == 2) ? wv : wo));
    dst = (s == 0) ? wqb : ((s == 1) ? wkb : ((s == 2) ? wvb : wob));
  }
  float4 f = *(const float4*)(src + off);
  ushort4 o;
  o.x = f2b(f.x); o.y = f2b(f.y); o.z = f2b(f.z); o.w = f2b(f.w);
  *(ushort4*)(dst + off) = o;
}

// ---------------------------------------------------------------------------
// Kernel 2: RoPE cos/sin table, [S][32] each, fp32.
// ---------------------------------------------------------------------------
__global__ __launch_bounds__(256) void k_ropetab(float* __restrict__ cosT, float* __restrict__ sinT) {
  int i = blockIdx.x * 256 + threadIdx.x;   // 0 .. 65536
  int s = i >> 5, j = i & 31;
  float invf = expf(-(float)j * 0.28782313662425574f);  // ln(1e4)/32
  float ang = (float)s * invf;
  float sn, cs;
  sincosf(ang, &sn, &cs);
  cosT[i] = cs;
  sinT[i] = sn;
}

// ---------------------------------------------------------------------------
// Kernel 3: fused QKV projection GEMM -- exact R14 config (measured optimum:
// 44.6us). BM=64 x BN=128, BK=64, 4 waves of 32x64, 24KB LDS, 6 blocks/CU.
// T21 granule swizzle: pre-swizzled source + XOR read (2-way, free).
// z=0: Q (RoPE+0.125*log2e -> Qr), z=1: K (RoPE -> Kr), z=2: V (per-wave
// 32x64 LDS transpose -> Vt kappa-order, private LDS regions).
// ---------------------------------------------------------------------------
__global__ __launch_bounds__(256) void k_gemmQKV(
    const u16* __restrict__ A0, const u16* __restrict__ W0,
    const u16* __restrict__ A1, const u16* __restrict__ W1,
    const u16* __restrict__ A2, const u16* __restrict__ W2,
    const float* __restrict__ cosT, const float* __restrict__ sinT,
    u16* __restrict__ Qr, u16* __restrict__ Kr, u16* __restrict__ Vt) {
  const int z = blockIdx.z;
  const u16* A = (z == 0) ? A0 : ((z == 1) ? A1 : A2);
  const u16* W = (z == 0) ? W0 : ((z == 1) ? W1 : W2);

  __shared__ u16 SL[12288];   // As = SL[0..4095] (64x64), Bs = SL[4096..12287] (128x64)
  u16* As = &SL[0];
  u16* Bs = &SL[4096];

  const int tid = threadIdx.x;
  const int wave = tid >> 6, lane = tid & 63;
  const int g = lane >> 4, cc = lane & 15;
  const int wm = wave >> 1, wn = wave & 1;
  const int row0 = blockIdx.x * 64, col0 = blockIdx.y * 128;

  const int rl8 = lane >> 3;
  const int sg8 = (lane & 7) ^ rl8;
  const u16* Asrc = A + (size_t)(row0 + wave * 16 + rl8) * 1024 + sg8 * 8;
  const u16* Wsrc = W + (size_t)(col0 + wave * 32 + rl8) * 1024 + sg8 * 8;
  u16* adst = &As[wave * 1024];
  u16* bdst = &Bs[wave * 2048];

  f32x4 acc[2][4] = {};

  for (int t = 0; t < 16; ++t) {
    const int k0 = t * 64;
    __syncthreads();
#pragma unroll
    for (int i = 0; i < 2; ++i)
      gload_lds16(Asrc + (size_t)i * 8192 + k0, adst + i * 512);
#pragma unroll
    for (int j = 0; j < 4; ++j)
      gload_lds16(Wsrc + (size_t)j * 8192 + k0, bdst + j * 512);
    __syncthreads();
#pragma unroll
    for (int hk = 0; hk < 2; ++hk) {
      bf16x8 af[2], bfv[4];
#pragma unroll
      for (int mi = 0; mi < 2; ++mi) {
        const int R = wm * 32 + mi * 16 + cc;
        af[mi] = *(const bf16x8*)&As[R * 64 + (((hk * 4 + g) ^ (R & 7)) * 8)];
      }
#pragma unroll
      for (int ni = 0; ni < 4; ++ni) {
        const int R = wn * 64 + ni * 16 + cc;
        bfv[ni] = *(const bf16x8*)&Bs[R * 64 + (((hk * 4 + g) ^ (R & 7)) * 8)];
      }
#pragma unroll
      for (int mi = 0; mi < 2; ++mi)
#pragma unroll
        for (int ni = 0; ni < 4; ++ni)
          acc[mi][ni] = mfma_bf16(af[mi], bfv[ni], acc[mi][ni]);
    }
  }

  const int hgl = (col0 >> 6) + wn;    // global head 0..15 (64 cols per wave)

  if (z < 2) {
    const float scale = (z == 0) ? 0.18033688011112042f : 1.0f;  // 0.125*log2e
    u16* dbase = (z == 0) ? Qr : Kr;
#pragma unroll
    for (int mi = 0; mi < 2; ++mi)
#pragma unroll
      for (int r = 0; r < 4; ++r) {
        const int gr = row0 + wm * 32 + mi * 16 + g * 4 + r;
        const int bb = gr >> 11, s = gr & 2047;
        const float cv0 = cosT[s * 32 + cc],      sv0 = sinT[s * 32 + cc];
        const float cv1 = cosT[s * 32 + cc + 16], sv1 = sinT[s * 32 + cc + 16];
        const float x0 = acc[mi][0][r], x1 = acc[mi][1][r];
        const float x2 = acc[mi][2][r], x3 = acc[mi][3][r];
        u16* dst = dbase + ((size_t)((bb * 16 + hgl) * 2048 + s)) * 64;
        dst[cc]      = f2b((x0 * cv0 - x2 * sv0) * scale);
        dst[cc + 16] = f2b((x1 * cv1 - x3 * sv1) * scale);
        dst[cc + 32] = f2b((x2 * cv0 + x0 * sv0) * scale);
        dst[cc + 48] = f2b((x3 * cv1 + x1 * sv1) * scale);
      }
  } else {
    // V: per-wave 32(s) x 64(dk) transpose via private LDS tl[32][72]
    u16* tl = &SL[wave * 2304];       // 32*72 = 2304 u16 per wave
    __syncthreads();
#pragma unroll
    for (int mi = 0; mi < 2; ++mi)
#pragma unroll
      for (int ni = 0; ni < 4; ++ni)
#pragma unroll
        for (int r = 0; r < 4; ++r)
          tl[(mi * 16 + g * 4 + r) * 72 + ni * 16 + cc] = f2b(acc[mi][ni][r]);
    asm volatile("s_waitcnt lgkmcnt(0)" ::: "memory");
    __builtin_amdgcn_sched_barrier(0);
#pragma unroll
    for (int p2 = 0; p2 < 8; ++p2) {
      const int dr = p2 * 8 + (lane >> 3);        // dk row 0..63
      const int scr = (lane & 7) * 4;             // s (rel to wave), %4 == 0
      ushort4 o;
      o.x = tl[(scr + 0) * 72 + dr];
      o.y = tl[(scr + 1) * 72 + dr];
      o.z = tl[(scr + 2) * 72 + dr];
      o.w = tl[(scr + 3) * 72 + dr];
      const int gsr = row0 + wm * 32 + scr;
      const int bb = gsr >> 11, sb = gsr & 2047;
      const int cch = sb >> 5, kap = sb & 31;
      const int pos = (cch << 5) + (((kap >> 2) & 3) << 3) + ((kap >> 4) << 2);
      *(ushort4*)(Vt + ((size_t)((bb * 16 + hgl) * 64 + dr)) * 2048 + pos) = o;
    }
  }
}

// ---------------------------------------------------------------------------
// Kernel 3b: output projection GEMM, fp32 out, exact R14 structure.
// ---------------------------------------------------------------------------
__global__ __launch_bounds__(256) void k_gemmO(
    const u16* __restrict__ A, const u16* __restrict__ W, float* __restrict__ O) {
  __shared__ u16 SL[12288];
  u16* As = &SL[0];
  u16* Bs = &SL[4096];

  const int tid = threadIdx.x;
  const int wave = tid >> 6, lane = tid & 63;
  const int g = lane >> 4, cc = lane & 15;
  const int wm = wave >> 1, wn = wave & 1;
  const int row0 = blockIdx.x * 64, col0 = blockIdx.y * 128;

  const int rl8 = lane >> 3;
  const int sg8 = (lane & 7) ^ rl8;
  const u16* Asrc = A + (size_t)(row0 + wave * 16 + rl8) * 1024 + sg8 * 8;
  const u16* Wsrc = W + (size_t)(col0 + wave * 32 + rl8) * 1024 + sg8 * 8;
  u16* adst = &As[wave * 1024];
  u16* bdst = &Bs[wave * 2048];

  f32x4 acc[2][4] = {};

  for (int t = 0; t < 16; ++t) {
    const int k0 = t * 64;
    __syncthreads();
#pragma unroll
    for (int i = 0; i < 2; ++i)
      gload_lds16(Asrc + (size_t)i * 8192 + k0, adst + i * 512);
#pragma unroll
    for (int j = 0; j < 4; ++j)
      gload_lds16(Wsrc + (size_t)j * 8192 + k0, bdst + j * 512);
    __syncthreads();
#pragma unroll
    for (int hk = 0; hk < 2; ++hk) {
      bf16x8 af[2], bfv[4];
#pragma unroll
      for (int mi = 0; mi < 2; ++mi) {
        const int R = wm * 32 + mi * 16 + cc;
        af[mi] = *(const bf16x8*)&As[R * 64 + (((hk * 4 + g) ^ (R & 7)) * 8)];
      }
#pragma unroll
      for (int ni = 0; ni < 4; ++ni) {
        const int R = wn * 64 + ni * 16 + cc;
        bfv[ni] = *(const bf16x8*)&Bs[R * 64 + (((hk * 4 + g) ^ (R & 7)) * 8)];
      }
#pragma unroll
      for (int mi = 0; mi < 2; ++mi)
#pragma unroll
        for (int ni = 0; ni < 4; ++ni)
          acc[mi][ni] = mfma_bf16(af[mi], bfv[ni], acc[mi][ni]);
    }
  }

#pragma unroll
  for (int mi = 0; mi < 2; ++mi)
#pragma unroll
    for (int ni = 0; ni < 4; ++ni)
#pragma unroll
      for (int r = 0; r < 4; ++r) {
        const int row = row0 + wm * 32 + mi * 16 + g * 4 + r;
        const int col = col0 + wn * 64 + ni * 16 + cc;
        O[row * 1024 + col] = acc[mi][ni][r];
      }
}

// ---------------------------------------------------------------------------
// Kernel 6: causal flash attention, fine split-K (2304 blocks, <=4 chunks
// per piece). No VGPR clamp. Native v_exp_f32. Stage issued before Q loads.
// ---------------------------------------------------------------------------
template <int M0, int M1>   // per 32-key half: 0=full, 1=tri(diag), 2=skip
__device__ __forceinline__ void attn_chunk64(
    const u16* __restrict__ kl, const u16* __restrict__ vl, int cc, int g,
    const bf16x8 qf[4],
    float& mold0, float& mold1, float& lsum0, float& lsum1,
    f32x4 ot0[4], f32x4 ot1[4]) {
  const int m7 = cc & 7;
  const int gA = (g ^ m7) * 8;
  const int gB = ((g + 4) ^ m7) * 8;

  f32x4 x0A0 = {}, x0B0 = {}, x0A1 = {}, x0B1 = {};
  {
    const u16* r0 = kl + cc * 64;
    const u16* r1 = kl + (16 + cc) * 64;
    bf16x8 k0 = *(const bf16x8*)(r0 + gA);
    bf16x8 k1 = *(const bf16x8*)(r0 + gB);
    bf16x8 k2 = *(const bf16x8*)(r1 + gA);
    bf16x8 k3 = *(const bf16x8*)(r1 + gB);
    x0A0 = mfma_bf16(k0, qf[0], x0A0);
    x0A0 = mfma_bf16(k1, qf[1], x0A0);
    x0B0 = mfma_bf16(k2, qf[0], x0B0);
    x0B0 = mfma_bf16(k3, qf[1], x0B0);
    x0A1 = mfma_bf16(k0, qf[2], x0A1);
    x0A1 = mfma_bf16(k1, qf[3], x0A1);
    x0B1 = mfma_bf16(k2, qf[2], x0B1);
    x0B1 = mfma_bf16(k3, qf[3], x0B1);
  }
  f32x4 x1A0 = {}, x1B0 = {}, x1A1 = {}, x1B1 = {};
  if (M1 != 2) {
    const u16* r0 = kl + (32 + cc) * 64;
    const u16* r1 = kl + (48 + cc) * 64;
    bf16x8 k0 = *(const bf16x8*)(r0 + gA);
    bf16x8 k1 = *(const bf16x8*)(r0 + gB);
    bf16x8 k2 = *(const bf16x8*)(r1 + gA);
    bf16x8 k3 = *(const bf16x8*)(r1 + gB);
    x1A0 = mfma_bf16(k0, qf[0], x1A0);
    x1A0 = mfma_bf16(k1, qf[1], x1A0);
    x1B0 = mfma_bf16(k2, qf[0], x1B0);
    x1B0 = mfma_bf16(k3, qf[1], x1B0);
    x1A1 = mfma_bf16(k0, qf[2], x1A1);
    x1A1 = mfma_bf16(k1, qf[3], x1A1);
    x1B1 = mfma_bf16(k2, qf[2], x1B1);
    x1B1 = mfma_bf16(k3, qf[3], x1B1);
  }

  float p0[16], p1[16];
#pragma unroll
  for (int r = 0; r < 4; ++r) {
    const int ka = g * 4 + r;
    float a0 = x0A0[r], b0 = x0B0[r], a1 = x0A1[r], b1 = x0B1[r];
    if (M0 == 1) {
      a0 = (ka <= cc) ? a0 : -30000.0f;
      b0 = -30000.0f;
      b1 = (ka <= cc) ? b1 : -30000.0f;
    }
    p0[r] = a0; p0[4 + r] = b0;
    p1[r] = a1; p1[4 + r] = b1;
  }
  if (M1 != 2) {
#pragma unroll
    for (int r = 0; r < 4; ++r) {
      const int ka = g * 4 + r;
      float a0 = x1A0[r], b0 = x1B0[r], a1 = x1A1[r], b1 = x1B1[r];
      if (M1 == 1) {
        a0 = (ka <= cc) ? a0 : -30000.0f;
        b0 = -30000.0f;
        b1 = (ka <= cc) ? b1 : -30000.0f;
      }
      p0[8 + r] = a0; p0[12 + r] = b0;
      p1[8 + r] = a1; p1[12 + r] = b1;
    }
  }

  float m0, m1;
  if (M1 != 2) {
    float t0a = fmaxf(fmaxf(p0[0], p0[1]), p0[2]);
    float t0b = fmaxf(fmaxf(p0[3], p0[4]), p0[5]);
    float t0c = fmaxf(fmaxf(p0[6], p0[7]), p0[8]);
    float t0d = fmaxf(fmaxf(p0[9], p0[10]), p0[11]);
    float t0e = fmaxf(fmaxf(p0[12], p0[13]), p0[14]);
    m0 = fmaxf(fmaxf(fmaxf(t0a, t0b), fmaxf(t0c, t0d)), fmaxf(t0e, p0[15]));
    float t1a = fmaxf(fmaxf(p1[0], p1[1]), p1[2]);
    float t1b = fmaxf(fmaxf(p1[3], p1[4]), p1[5]);
    float t1c = fmaxf(fmaxf(p1[6], p1[7]), p1[8]);
    float t1d = fmaxf(fmaxf(p1[9], p1[10]), p1[11]);
    float t1e = fmaxf(fmaxf(p1[12], p1[13]), p1[14]);
    m1 = fmaxf(fmaxf(fmaxf(t1a, t1b), fmaxf(t1c, t1d)), fmaxf(t1e, p1[15]));
  } else {
    float t0a = fmaxf(fmaxf(p0[0], p0[1]), p0[2]);
    float t0b = fmaxf(fmaxf(p0[3], p0[4]), p0[5]);
    m0 = fmaxf(fmaxf(p0[6], p0[7]), fmaxf(t0a, t0b));
    float t1a = fmaxf(fmaxf(p1[0], p1[1]), p1[2]);
    float t1b = fmaxf(fmaxf(p1[3], p1[4]), p1[5]);
    m1 = fmaxf(fmaxf(p1[6], p1[7]), fmaxf(t1a, t1b));
  }

  // shuffle-free defer test (mold is row-uniform by construction)
  if (!__all((m0 <= mold0 + 11.5f) && (m1 <= mold1 + 11.5f))) {
    float M0v = fmaxf(m0, __shfl_xor(m0, 16));
    M0v = fmaxf(M0v, __shfl_xor(M0v, 32));
    float M1v = fmaxf(m1, __shfl_xor(m1, 16));
    M1v = fmaxf(M1v, __shfl_xor(M1v, 32));
    M0v = fmaxf(mold0, M0v);
    M1v = fmaxf(mold1, M1v);
    const float al0 = EXP2(mold0 - M0v), al1 = EXP2(mold1 - M1v);
    mold0 = M0v; mold1 = M1v;
    lsum0 *= al0; lsum1 *= al1;
#pragma unroll
    for (int dc = 0; dc < 4; ++dc) { ot0[dc] *= al0; ot1[dc] *= al1; }
  }

  float rs0 = 0.f, rs1 = 0.f;
  bf16x8 a0v, a1v, b0v2, b1v2;
#pragma unroll
  for (int j = 0; j < 8; ++j) {
    float e0 = EXP2(p0[j] - mold0);
    float e1 = EXP2(p1[j] - mold1);
    rs0 += e0; rs1 += e1;
    a0v[j] = (__bf16)e0;
    a1v[j] = (__bf16)e1;
  }
  if (M1 != 2) {
#pragma unroll
    for (int j = 0; j < 8; ++j) {
      float e0 = EXP2(p0[8 + j] - mold0);
      float e1 = EXP2(p1[8 + j] - mold1);
      rs0 += e0; rs1 += e1;
      b0v2[j] = (__bf16)e0;
      b1v2[j] = (__bf16)e1;
    }
  }
  lsum0 += rs0; lsum1 += rs1;

#pragma unroll
  for (int dc = 0; dc < 4; ++dc) {
    bf16x8 vv = *(const bf16x8*)(vl + (dc * 16 + cc) * 64 + gA);
    ot0[dc] = mfma_bf16(vv, a0v, ot0[dc]);
    ot1[dc] = mfma_bf16(vv, a1v, ot1[dc]);
  }
  if (M1 != 2) {
#pragma unroll
    for (int dc = 0; dc < 4; ++dc) {
      bf16x8 vv = *(const bf16x8*)(vl + (dc * 16 + cc) * 64 + gB);
      ot0[dc] = mfma_bf16(vv, b0v2, ot0[dc]);
      ot1[dc] = mfma_bf16(vv, b1v2, ot1[dc]);
    }
  }
}

__global__ __launch_bounds__(256) void k_attn(
    const u16* __restrict__ Qr, const u16* __restrict__ Kr,
    const u16* __restrict__ Vt, u16* __restrict__ Oc,
    u16* __restrict__ PO, float* __restrict__ PML) {
  __shared__ u16 Kl[2][4096];   // [buf][64 keys x 64 d], granule-swizzled
  __shared__ u16 Vl[2][4096];   // [buf][64 d x 64 keys], granule-swizzled

  const int x = blockIdx.x;          // 0..2303
  const int bh = x & 31;             // all pieces of head bh -> XCD bh%8
  const int u = 71 - (x >> 5);       // heavy pieces first
  const int tile = PT_tile[u];
  const int c0 = PT_c0[u];
  const int c1 = PT_c1[u];
  const int slot = u - 2;            // <0 => direct output (tiles 0,1)
  const int b = bh >> 4, h = bh & 15;
  const int tid = threadIdx.x;
  const int w = tid >> 6;
  const int lane = tid & 63;
  const int g = lane >> 4, cc = lane & 15;

  const int qrow0 = tile * 128 + w * 32;
  const int myDiag = 2 * tile + (w >> 1);

  const u16* Kp = Kr + (size_t)bh * (Sdim * 64);
  const u16* Vp = Vt + (size_t)bh * (64 * Sdim);
  const u16* Qp = Qr + (size_t)(bh * Sdim + qrow0) * 64;

  // staging sources (pre-swizzled, T21): granule ^= row_local&7
  const int rloc = lane >> 3;
  const int sg = (lane & 7) ^ rloc;
  const u16* kS = Kp + (size_t)(w * 16 + rloc) * 64 + sg * 8;
  const u16* vS = Vp + (size_t)(w * 16 + rloc) * 2048 + sg * 8;

  auto stageKV = [&](int t, int buf) {
    const size_t ko = (size_t)t * 4096;
    const size_t vo = (size_t)t * 64;
    gload_lds16(kS + ko, &Kl[buf][w * 1024]);
    gload_lds16(kS + ko + 512, &Kl[buf][w * 1024 + 512]);
    gload_lds16(vS + vo, &Vl[buf][w * 1024]);
    gload_lds16(vS + vo + 16384, &Vl[buf][w * 1024 + 512]);
  };

  stageKV(c0, c0 & 1);               // earliest DMA start

  bf16x8 qf[4];
  qf[0] = *(const bf16x8*)(Qp + cc * 64 + g * 8);
  qf[1] = *(const bf16x8*)(Qp + cc * 64 + g * 8 + 32);
  qf[2] = *(const bf16x8*)(Qp + (16 + cc) * 64 + g * 8);
  qf[3] = *(const bf16x8*)(Qp + (16 + cc) * 64 + g * 8 + 32);

  float mold0 = -1e30f, mold1 = -1e30f, lsum0 = 0.f, lsum1 = 0.f;
  f32x4 ot0[4] = {}, ot1[4] = {};

  for (int t = c0; t < c1; ++t) {
    __syncthreads();                 // drains stage(t)
    if (t + 1 < c1) stageKV(t + 1, (t + 1) & 1);
    if (t <= myDiag) {
      const u16* kl = &Kl[t & 1][0];
      const u16* vl = &Vl[t & 1][0];
      if (t < myDiag)
        attn_chunk64<0, 0>(kl, vl, cc, g, qf, mold0, mold1, lsum0, lsum1, ot0, ot1);
      else if (w & 1)
        attn_chunk64<0, 1>(kl, vl, cc, g, qf, mold0, mold1, lsum0, lsum1, ot0, ot1);
      else
        attn_chunk64<1, 2>(kl, vl, cc, g, qf, mold0, mold1, lsum0, lsum1, ot0, ot1);
    }
  }

  float l0 = lsum0 + __shfl_xor(lsum0, 16);
  l0 += __shfl_xor(l0, 32);
  float l1 = lsum1 + __shfl_xor(lsum1, 16);
  l1 += __shfl_xor(l1, 32);

  if (slot < 0) {
    const float rl0 = 1.0f / l0, rl1 = 1.0f / l1;
    u16* dst0 = Oc + (size_t)(b * Sdim + qrow0 + cc) * Ddim + h * 64 + g * 4;
    u16* dst1 = dst0 + 16 * Ddim;
#pragma unroll
    for (int dc = 0; dc < 4; ++dc) {
      ushort4 o0, o1;
      o0.x = f2b(ot0[dc][0] * rl0);
      o0.y = f2b(ot0[dc][1] * rl0);
      o0.z = f2b(ot0[dc][2] * rl0);
      o0.w = f2b(ot0[dc][3] * rl0);
      o1.x = f2b(ot1[dc][0] * rl1);
      o1.y = f2b(ot1[dc][1] * rl1);
      o1.z = f2b(ot1[dc][2] * rl1);
      o1.w = f2b(ot1[dc][3] * rl1);
      *(ushort4*)(dst0 + dc * 16) = o0;
      *(ushort4*)(dst1 + dc * 16) = o1;
    }
  } else {
    const int sgl = bh * 70 + slot;
    u16* po0 = PO + (size_t)sgl * 8192 + (w * 32 + cc) * 64;
    u16* po1 = po0 + 16 * 64;
#pragma unroll
    for (int dc = 0; dc < 4; ++dc) {
      ushort4 o0, o1;
      o0.x = f2b(ot0[dc][0]); o0.y = f2b(ot0[dc][1]);
      o0.z = f2b(ot0[dc][2]); o0.w = f2b(ot0[dc][3]);
      o1.x = f2b(ot1[dc][0]); o1.y = f2b(ot1[dc][1]);
      o1.z = f2b(ot1[dc][2]); o1.w = f2b(ot1[dc][3]);
      *(ushort4*)(po0 + dc * 16 + g * 4) = o0;
      *(ushort4*)(po1 + dc * 16 + g * 4) = o1;
    }
    if (g == 0) {
      float* ml = PML + (size_t)sgl * 256 + (w * 32 + cc) * 2;
      ml[0] = mold0;
      ml[1] = l0;
      ml[32] = mold1;
      ml[33] = l1;
    }
  }
}

// ---------------------------------------------------------------------------
// Kernel 7: combine split-K partials for tiles 2..15 (2-8 pieces each).
// R17 post-mortem: old layout (thread=row, 8B per slot per c-iter, 8 slots
// interleaved) had a 128KB instantaneous line footprint -> L1/L2 thrash ->
// 3x HBM over-fetch, 58us. New layout: 256 threads, thread=(row, col-half);
// each thread reads 64B CONTIGUOUS per slot (4 x uint4, full-line consumption
// temporally adjacent) and accumulates 32 outputs in registers. All arrays
// statically indexed (unrolled j<8 with uniform cnt guard).
// ---------------------------------------------------------------------------
__global__ __launch_bounds__(256) void k_comb(
    const u16* __restrict__ PO, const float* __restrict__ PML,
    u16* __restrict__ Oc) {
  const int x = blockIdx.x;          // 0..447: bh fastest (XCD-local)
  const int bh = x & 31;
  const int tidx = x >> 5;           // 0..13
  const int tile = tidx + 2;
  const int cnt = CB_cnt[tidx];
  const int sgb = bh * 70 + CB_base[tidx];
  const int b = bh >> 4, h = bh & 15;
  const int t = threadIdx.x;         // 0..255
  const int r = t >> 1;              // row 0..127
  const int hh = t & 1;              // column half (32 cols)

  float m[8], l[8];
#pragma unroll
  for (int j = 0; j < 8; ++j) {
    if (j < cnt) {
      const float* ml = PML + (size_t)(sgb + j) * 256 + r * 2;
      m[j] = ml[0];
      l[j] = ml[1];
    } else { m[j] = -1e30f; l[j] = 0.f; }
  }
  float M = m[0];
#pragma unroll
  for (int j = 1; j < 8; ++j) M = fmaxf(M, m[j]);
  float wgt[8];
  float ltot = 0.f;
#pragma unroll
  for (int j = 0; j < 8; ++j) {
    wgt[j] = (j < cnt) ? EXP2(m[j] - M) : 0.f;
    ltot += wgt[j] * l[j];
  }
  const float inv = 1.0f / ltot;
#pragma unroll
  for (int j = 0; j < 8; ++j) wgt[j] *= inv;

  float acc[32];
#pragma unroll
  for (int i = 0; i < 32; ++i) acc[i] = 0.f;

#pragma unroll
  for (int j = 0; j < 8; ++j) {
    if (j < cnt) {
      const u16* src = PO + (size_t)(sgb + j) * 8192 + r * 64 + hh * 32;
      const float wj = wgt[j];
#pragma unroll
      for (int i = 0; i < 4; ++i) {
        union { uint4 u; u16 s[8]; } v;
        v.u = *(const uint4*)(src + i * 8);
#pragma unroll
        for (int e = 0; e < 8; ++e)
          acc[i * 8 + e] += wj * b2f(v.s[e]);
      }
    }
  }

  u16* dst = Oc + (size_t)(b * Sdim + tile * 128 + r) * Ddim + h * 64 + hh * 32;
#pragma unroll
  for (int i = 0; i < 4; ++i) {
    union { uint4 u; u16 s[8]; } o;
#pragma unroll
    for (int e = 0; e < 8; ++e) o.s[e] = f2b(acc[i * 8 + e]);
    *(uint4*)(dst + i * 8) = o.u;
  }
}

// ---------------------------------------------------------------------------
extern "C" void kernel_launch(void* const* d_in, const int* in_sizes, int n_in,
                              void* d_out, int out_size, void* d_ws, size_t ws_size,
                              hipStream_t stream) {
  const float* q = (const float*)d_in[0];
  const float* k = (const float*)d_in[1];
  const float* v = (const float*)d_in[2];
  const float* wq = (const float*)d_in[3];
  const float* wk = (const float*)d_in[4];
  const float* wv = (const float*)d_in[5];
  const float* wo = (const float*)d_in[6];
  float* out = (float*)d_out;

  uint8_t* ws = (uint8_t*)d_ws;
  const size_t MiB = 1ull << 20;
  // Liveness map:
  //  phase 1 (convert/gemmQKV): qb 0-8, kb 8-16, vb 16-24, wqb/wkb/wvb 24-30,
  //                             wob 48-50 (LIVE until k_gemmO!), tables 88+.
  //  phase 2 (attn/comb):       PO 0-36.7, PML 40-42.3 (over dead qb/kb/vb/wq..),
  //                             Qr 56, Kr 64, Vt 72, Oc 80-88.
  //  phase 3 (gemmO):           Oc + wob(48-50) -> out.
  u16* qb  = (u16*)(ws + 0 * MiB);
  u16* kb  = (u16*)(ws + 8 * MiB);
  u16* vb  = (u16*)(ws + 16 * MiB);
  u16* wqb = (u16*)(ws + 24 * MiB);
  u16* wkb = (u16*)(ws + 26 * MiB);
  u16* wvb = (u16*)(ws + 28 * MiB);
  u16* wob = (u16*)(ws + 48 * MiB);      // out of PO's range (R16 bug fix)
  u16* Qr  = (u16*)(ws + 56 * MiB);
  u16* Kr  = (u16*)(ws + 64 * MiB);
  u16* Vt  = (u16*)(ws + 72 * MiB);
  u16* Oc  = (u16*)(ws + 80 * MiB);
  float* cosT = (float*)(ws + 88 * MiB);
  float* sinT = (float*)(ws + 88 * MiB + 256 * 1024);
  u16*   PO  = (u16*)(ws + 0 * MiB);     // 2240 slots * 8192 bf16 = 36.7 MB
  float* PML = (float*)(ws + 40 * MiB);  // 2240 * 256 f32 = 2.29 MB

  k_convert<<<16384, 256, 0, stream>>>(q, k, v, wq, wk, wv, wo,
                                       qb, kb, vb, wqb, wkb, wvb, wob);
  k_ropetab<<<256, 256, 0, stream>>>(cosT, sinT);
  k_gemmQKV<<<dim3(64, 8, 3), 256, 0, stream>>>(qb, wqb, kb, wkb, vb, wvb,
                                                cosT, sinT, Qr, Kr, Vt);
  k_attn<<<2304, 256, 0, stream>>>(Qr, Kr, Vt, Oc, PO, PML);
  k_comb<<<448, 256, 0, stream>>>(PO, PML, Oc);
  k_gemmO<<<dim3(64, 8), 256, 0, stream>>>(Oc, wob, out);
}